// Round 11
// baseline (61.755 us; speedup 1.0000x reference)
//
#include <hip/hip_runtime.h>
#include <stdint.h>

// QuantConv1D (binary, K=3, Cin=128, Cout=256, VALID) + bias + BN(inference)
// via i8 MFMA: out[(b,t)][co] = dot * inv[co] + Cb[co],
// dot = sum_{tap,cin} sign(x[b,t+tap,cin]) * sign(ker[tap,cin,co]) (exact i32).
//
// R11: operand-swapped MFMA (D = W·X). C/D col(lane&31) = t, reg rows = co,
// so reg-quads are contiguous co -> DIRECT float4 stores from the
// accumulator. No Ct transpose, no barrier after staging => no vmcnt(0)
// drains in the epilogue (R10's suspected killer).
//  - v_mfma_i32_32x32x32_i8; A-frag = W from co-major kb8 (12 b128/lane,
//    loaded before staging); B-frag = X rows from LDS (16B-slot XOR swizzle).
//  - stores: plain (not NT): 32B segments/lane-pair merge to full lines in L2.
// C/D layout (HW-verified m74/m101): col=lane&31, row=(reg&3)+8*(reg>>2)+4*(lane>>5).

#define B 64
#define T 2048
#define CIN 128
#define COUT 256
#define KW 3
#define TOUT (T - KW + 1)        // 2046
#define MROWS 64                 // output t-rows per block
#define AROWS (MROWS + KW - 1)   // 66 staged x-rows
#define NBLK_T 32                // t-windows per batch (last overlaps: t0=1982)

typedef int   i32x4  __attribute__((ext_vector_type(4)));
typedef int   i32x16 __attribute__((ext_vector_type(16)));
typedef float f32x4  __attribute__((ext_vector_type(4)));

// ---- pack kernel signs (i8 +1/-1, co-major) + fold BN affine ----
// kb8[co*384 + tap*128 + cin]
__global__ __launch_bounds__(256) void pack_w_kernel(const float* __restrict__ ker,
                                                     const float* __restrict__ bias,
                                                     const float* __restrict__ beta,
                                                     const float* __restrict__ mean,
                                                     const float* __restrict__ var,
                                                     uint8_t* __restrict__ kb8,
                                                     float* __restrict__ Ainv,
                                                     float* __restrict__ Cb) {
    const int tap = blockIdx.x >> 2;    // 0..2
    const int q   = blockIdx.x & 3;     // cin quarter
    const int co  = threadIdx.x;        // 0..255
    #pragma unroll
    for (int j = 0; j < 8; ++j) {
        int cin0 = q * 32 + j * 4;
        const float* s = ker + ((size_t)(tap * CIN + cin0)) * COUT + co;
        uint32_t w = (s[0]                >= 0.f ? 0x01u : 0xFFu)
                   | ((s[(size_t)COUT]     >= 0.f ? 0x01u : 0xFFu) << 8)
                   | ((s[(size_t)2 * COUT] >= 0.f ? 0x01u : 0xFFu) << 16)
                   | ((s[(size_t)3 * COUT] >= 0.f ? 0x01u : 0xFFu) << 24);
        *(uint32_t*)(kb8 + (size_t)co * 384 + tap * 128 + cin0) = w;
    }
    if (blockIdx.x == 0) {
        float inv = 1.0f / sqrtf(var[co] + 1e-3f);
        Ainv[co] = inv;
        Cb[co]   = (bias[co] - mean[co]) * inv + beta[co];
    }
}

// ---- fused stage + swapped MFMA conv + direct-store epilogue ----
__global__ __launch_bounds__(512) void conv_mfma_kernel(const float* __restrict__ x,
                                                        const uint8_t* __restrict__ kb8,
                                                        const float* __restrict__ Ainv,
                                                        const float* __restrict__ Cb,
                                                        float* __restrict__ out) {
    const int tid = threadIdx.x;
    const int l   = tid & 63;
    const int h   = l >> 5;              // k-half
    const int ln  = l & 31;
    const int wv  = tid >> 6;            // 0..7: cout tile wv*32..+31
    const int bb  = blockIdx.x >> 5;     // batch
    const int wi  = blockIdx.x & 31;     // t-window
    const int t0  = (wi < NBLK_T - 1) ? wi * MROWS : (TOUT - MROWS);  // 1982 last

    __shared__ uint32_t As[AROWS * 32];  // 66 rows x 128B sign-i8, 16B-slot swizzle

    // --- A-frags (weights): this lane = co row (wv*32+ln), k-half h ---
    // Af[tap*4+s] = 16 i8 at k = tap*128 + s*32 + h*16  (long-latency first)
    i32x4 Af[12];
    {
        const uint8_t* ap = kb8 + (size_t)(wv * 32 + ln) * 384 + h * 16;
        #pragma unroll
        for (int a = 0; a < 12; ++a)
            Af[a] = *(const i32x4*)(ap + a * 32);
    }

    // --- stage x -> sign-i8 LDS (coalesced float4 reads) ---
    {
        const float* xb = x + ((size_t)bb * T + t0) * CIN;
        for (int idx = tid; idx < AROWS * 32; idx += 512) {
            int row = idx >> 5, c4 = idx & 31;
            const float4 v = *(const float4*)(xb + (size_t)row * CIN + c4 * 4);
            uint32_t w = (v.x >= 0.f ? 0x01u : 0xFFu)
                       | ((v.y >= 0.f ? 0x01u : 0xFFu) << 8)
                       | ((v.z >= 0.f ? 0x01u : 0xFFu) << 16)
                       | ((v.w >= 0.f ? 0x01u : 0xFFu) << 24);
            int slot = (c4 >> 2) ^ (row & 7);            // 16B-slot swizzle
            As[row * 32 + slot * 4 + (c4 & 3)] = w;
        }
    }
    __syncthreads();

    // --- K-loop: 3 taps x 4 K32-steps x 2 t-tiles = 24 MFMA (swapped: a=W, b=X) ---
    i32x16 acc0 = {}, acc1 = {};
    const char* Ab = (const char*)As;
    #pragma unroll
    for (int tap = 0; tap < KW; ++tap) {
        #pragma unroll
        for (int s = 0; s < 4; ++s) {
            const int slot = s * 2 + h;                  // logical 16B slot
            const i32x4 af = Af[tap * 4 + s];
            const int r0 = ln + tap;                     // t-tile 0 rows
            i32x4 B0 = *(const i32x4*)(Ab + r0 * 128 + ((slot ^ (r0 & 7)) << 4));
            acc0 = __builtin_amdgcn_mfma_i32_32x32x32_i8(af, B0, acc0, 0, 0, 0);
            const int r1 = r0 + 32;                      // t-tile 1 rows
            i32x4 B1 = *(const i32x4*)(Ab + r1 * 128 + ((slot ^ (r1 & 7)) << 4));
            acc1 = __builtin_amdgcn_mfma_i32_32x32x32_i8(af, B1, acc1, 0, 0, 0);
        }
    }

    // --- epilogue: direct float4 stores from acc (col=t, reg rows=co) ---
    // reg-quad g covers co = wv*32 + g*8 + 4h + {0..3}
    f32x4 ai[4], cbv[4];
    #pragma unroll
    for (int g = 0; g < 4; ++g) {
        ai[g]  = *(const f32x4*)(Ainv + wv * 32 + g * 8 + 4 * h);
        cbv[g] = *(const f32x4*)(Cb   + wv * 32 + g * 8 + 4 * h);
    }
    float* ob = out + ((size_t)bb * TOUT + t0 + ln) * COUT + wv * 32 + 4 * h;
    #pragma unroll
    for (int g = 0; g < 4; ++g) {
        f32x4 o0, o1;
        #pragma unroll
        for (int j = 0; j < 4; ++j) {
            o0[j] = fmaf((float)acc0[g * 4 + j], ai[g][j], cbv[g][j]);
            o1[j] = fmaf((float)acc1[g * 4 + j], ai[g][j], cbv[g][j]);
        }
        *(f32x4*)(ob + g * 8)                        = o0;   // t-tile 0
        *(f32x4*)(ob + (size_t)32 * COUT + g * 8)    = o1;   // t-tile 1
    }
}

extern "C" void kernel_launch(void* const* d_in, const int* in_sizes, int n_in,
                              void* d_out, int out_size, void* d_ws, size_t ws_size,
                              hipStream_t stream) {
    const float* x    = (const float*)d_in[0];
    const float* ker  = (const float*)d_in[1];
    const float* bias = (const float*)d_in[2];
    const float* beta = (const float*)d_in[3];
    const float* mean = (const float*)d_in[4];
    const float* var  = (const float*)d_in[5];
    float* out = (float*)d_out;

    // workspace: kb8 (96 KB) | Ainv (1 KB) | Cb (1 KB)
    uint8_t* kb8  = (uint8_t*)d_ws;
    float*   Ainv = (float*)(kb8 + (size_t)COUT * 384);
    float*   Cb   = Ainv + COUT;

    pack_w_kernel<<<KW * 4, 256, 0, stream>>>(ker, bias, beta, mean, var, kb8, Ainv, Cb);
    conv_mfma_kernel<<<B * NBLK_T, 512, 0, stream>>>(x, kb8, Ainv, Cb, out);
}

// Round 12
// 55.406 us; speedup vs baseline: 1.1146x; 1.1146x over previous
//
#include <hip/hip_runtime.h>
#include <stdint.h>

// QuantConv1D (binary, K=3, Cin=128, Cout=256, VALID) + bias + BN(inference)
// via i8 MFMA: out[(b,t)][co] = dot * inv[co] + Cb[co],
// dot = sum_{tap,cin} sign(x[b,t+tap,cin]) * sign(ker[tap,cin,co]) (exact i32).
//
// R12: R10 core (A = X from LDS, B = W prefetched regs, K=32, 24 MFMA/wave)
// with the layout-natural epilogue: lane = co (contiguous in memory), so each
// acc reg stores as half-wave 128B full-line segments via PLAIN dword stores.
// No LDS transpose, no epilogue barriers (R10's drain killer), no NT 4B
// granules (R9's killer), no 16B/1KB scatter (R11's killer).
// C/D layout (HW-verified m74/m101, shape-determined): col=lane&31,
// row=(reg&3)+8*(reg>>2)+4*(lane>>5).

#define B 64
#define T 2048
#define CIN 128
#define COUT 256
#define KW 3
#define TOUT (T - KW + 1)        // 2046
#define MROWS 64                 // output t-rows per block
#define AROWS (MROWS + KW - 1)   // 66 staged x-rows
#define NBLK_T 32                // t-windows per batch (last overlaps: t0=1982)

typedef int   i32x4  __attribute__((ext_vector_type(4)));
typedef int   i32x16 __attribute__((ext_vector_type(16)));

// ---- pack kernel signs (i8 +1/-1, co-major) + fold BN affine ----
// kb8[co*384 + tap*128 + cin]
__global__ __launch_bounds__(256) void pack_w_kernel(const float* __restrict__ ker,
                                                     const float* __restrict__ bias,
                                                     const float* __restrict__ beta,
                                                     const float* __restrict__ mean,
                                                     const float* __restrict__ var,
                                                     uint8_t* __restrict__ kb8,
                                                     float* __restrict__ Ainv,
                                                     float* __restrict__ Cb) {
    const int tap = blockIdx.x >> 2;    // 0..2
    const int q   = blockIdx.x & 3;     // cin quarter
    const int co  = threadIdx.x;        // 0..255
    #pragma unroll
    for (int j = 0; j < 8; ++j) {
        int cin0 = q * 32 + j * 4;
        const float* s = ker + ((size_t)(tap * CIN + cin0)) * COUT + co;
        uint32_t w = (s[0]                >= 0.f ? 0x01u : 0xFFu)
                   | ((s[(size_t)COUT]     >= 0.f ? 0x01u : 0xFFu) << 8)
                   | ((s[(size_t)2 * COUT] >= 0.f ? 0x01u : 0xFFu) << 16)
                   | ((s[(size_t)3 * COUT] >= 0.f ? 0x01u : 0xFFu) << 24);
        *(uint32_t*)(kb8 + (size_t)co * 384 + tap * 128 + cin0) = w;
    }
    if (blockIdx.x == 0) {
        float inv = 1.0f / sqrtf(var[co] + 1e-3f);
        Ainv[co] = inv;
        Cb[co]   = (bias[co] - mean[co]) * inv + beta[co];
    }
}

// ---- fused stage + MFMA conv + direct line-segment stores ----
__global__ __launch_bounds__(512) void conv_mfma_kernel(const float* __restrict__ x,
                                                        const uint8_t* __restrict__ kb8,
                                                        const float* __restrict__ Ainv,
                                                        const float* __restrict__ Cb,
                                                        float* __restrict__ out) {
    const int tid = threadIdx.x;
    const int l   = tid & 63;
    const int h   = l >> 5;              // k-half / t-row offset selector
    const int ln  = l & 31;
    const int wv  = tid >> 6;            // 0..7: cout tile wv*32..+31
    const int bb  = blockIdx.x >> 5;     // batch
    const int wi  = blockIdx.x & 31;     // t-window
    const int t0  = (wi < NBLK_T - 1) ? wi * MROWS : (TOUT - MROWS);  // 1982 last

    __shared__ uint32_t As[AROWS * 32];  // 66 rows x 128B sign-i8, 16B-slot swizzle

    // --- B-frags (weights) first: lane = col wv*32+ln, k-half h (long latency) ---
    const int col = (wv << 5) + ln;
    i32x4 Bf[12];
    {
        const uint8_t* bp = kb8 + (size_t)col * 384 + h * 16;
        #pragma unroll
        for (int a = 0; a < 12; ++a)
            Bf[a] = *(const i32x4*)(bp + a * 32);
    }
    const float ainv = Ainv[col];
    const float cb   = Cb[col];

    // --- stage x -> sign-i8 LDS (coalesced float4 reads) ---
    {
        const float* xb = x + ((size_t)bb * T + t0) * CIN;
        for (int idx = tid; idx < AROWS * 32; idx += 512) {
            int row = idx >> 5, c4 = idx & 31;
            const float4 v = *(const float4*)(xb + (size_t)row * CIN + c4 * 4);
            uint32_t w = (v.x >= 0.f ? 0x01u : 0xFFu)
                       | ((v.y >= 0.f ? 0x01u : 0xFFu) << 8)
                       | ((v.z >= 0.f ? 0x01u : 0xFFu) << 16)
                       | ((v.w >= 0.f ? 0x01u : 0xFFu) << 24);
            int slot = (c4 >> 2) ^ (row & 7);            // 16B-slot swizzle
            As[row * 32 + slot * 4 + (c4 & 3)] = w;
        }
    }
    __syncthreads();

    // --- K-loop: 3 taps x 4 K32-steps x 2 t-tiles = 24 MFMA (A=X, B=W) ---
    i32x16 acc0 = {}, acc1 = {};
    const char* Ab = (const char*)As;
    #pragma unroll
    for (int tap = 0; tap < KW; ++tap) {
        #pragma unroll
        for (int s = 0; s < 4; ++s) {
            const int slot = s * 2 + h;                  // logical 16B slot
            const i32x4 bf = Bf[tap * 4 + s];
            const int r0 = ln + tap;                     // t-tile 0 rows
            i32x4 A0 = *(const i32x4*)(Ab + r0 * 128 + ((slot ^ (r0 & 7)) << 4));
            acc0 = __builtin_amdgcn_mfma_i32_32x32x32_i8(A0, bf, acc0, 0, 0, 0);
            const int r1 = r0 + 32;                      // t-tile 1 rows
            i32x4 A1 = *(const i32x4*)(Ab + r1 * 128 + ((slot ^ (r1 & 7)) << 4));
            acc1 = __builtin_amdgcn_mfma_i32_32x32x32_i8(A1, bf, acc1, 0, 0, 0);
        }
    }

    // --- epilogue: plain dword stores; half-wave = 128B full-line segment ---
    // value (t = t0 + trow(+32), co = col); trow = (reg&3)+8*(reg>>2)+4h
    float* ob = out + ((size_t)bb * TOUT + t0) * COUT + col;
    #pragma unroll
    for (int reg = 0; reg < 16; ++reg) {
        const int trow = (reg & 3) + 8 * (reg >> 2) + 4 * h;
        ob[(size_t)trow * COUT]        = fmaf((float)acc0[reg], ainv, cb);
        ob[(size_t)(32 + trow) * COUT] = fmaf((float)acc1[reg], ainv, cb);
    }
}

extern "C" void kernel_launch(void* const* d_in, const int* in_sizes, int n_in,
                              void* d_out, int out_size, void* d_ws, size_t ws_size,
                              hipStream_t stream) {
    const float* x    = (const float*)d_in[0];
    const float* ker  = (const float*)d_in[1];
    const float* bias = (const float*)d_in[2];
    const float* beta = (const float*)d_in[3];
    const float* mean = (const float*)d_in[4];
    const float* var  = (const float*)d_in[5];
    float* out = (float*)d_out;

    // workspace: kb8 (96 KB) | Ainv (1 KB) | Cb (1 KB)
    uint8_t* kb8  = (uint8_t*)d_ws;
    float*   Ainv = (float*)(kb8 + (size_t)COUT * 384);
    float*   Cb   = Ainv + COUT;

    pack_w_kernel<<<KW * 4, 256, 0, stream>>>(ker, bias, beta, mean, var, kb8, Ainv, Cb);
    conv_mfma_kernel<<<B * NBLK_T, 512, 0, stream>>>(x, kb8, Ainv, Cb, out);
}